// Round 1
// baseline (275.980 us; speedup 1.0000x reference)
//
#include <hip/hip_runtime.h>

#define DEV static __device__ __forceinline__

using bf16x8 = __attribute__((ext_vector_type(8))) short;
using f32x4  = __attribute__((ext_vector_type(4))) float;

// fp32 -> bf16 bits, round-to-nearest-even (inputs are finite)
DEV unsigned short f2bf(float f) {
  union { float f; unsigned u; } v; v.f = f;
  return (unsigned short)((v.u + 0x7fffu + ((v.u >> 16) & 1u)) >> 16);
}
DEV unsigned pk2(float lo, float hi) {
  return (unsigned)f2bf(lo) | ((unsigned)f2bf(hi) << 16);
}

DEV f32x4 mfma_bf16(bf16x8 a, bf16x8 b, f32x4 c) {
  return __builtin_amdgcn_mfma_f32_16x16x32_bf16(a, b, c, 0, 0, 0);
}

// ---------------------------------------------------------------------------
// Fused QKV projection GEMM.  C[r][o] = sum_k A[r][k] * W[o][k]
// A: [4096][1024] fp32 (x1 for z=0, x2 for z=1,2), W: [1024][1024] fp32.
// z=0 -> qproj fp32 flat; z=1 -> kproj fp32 flat; z=2 -> v bf16 [B,H,M,D].
// Tile 128x128, BK=64, 4 waves (2x2), XOR-swizzled LDS.
// ---------------------------------------------------------------------------
__global__ __launch_bounds__(256, 2)
void gemm_qkv(const float* __restrict__ x1, const float* __restrict__ x2,
              const float* __restrict__ Wq, const float* __restrict__ Wk,
              const float* __restrict__ Wv,
              float* __restrict__ qproj, float* __restrict__ kproj,
              unsigned short* __restrict__ vb)
{
  __shared__ short As[128 * 64];
  __shared__ short Bs[128 * 64];
  const int tid = threadIdx.x;
  const int l = tid & 63, w = tid >> 6;
  const int wr = w >> 1, wc = w & 1;
  const int z = blockIdx.z;
  const float* A = (z == 0) ? x1 : x2;
  const float* W = (z == 0) ? Wq : (z == 1 ? Wk : Wv);
  const int brow = blockIdx.y * 128, bcol = blockIdx.x * 128;

  const f32x4 zero = {0.f, 0.f, 0.f, 0.f};
  f32x4 acc[4][4];
#pragma unroll
  for (int mi = 0; mi < 4; ++mi)
#pragma unroll
    for (int ni = 0; ni < 4; ++ni) acc[mi][ni] = zero;

  for (int kt = 0; kt < 16; ++kt) {
#pragma unroll
    for (int i = 0; i < 4; ++i) {
      int c = i * 256 + tid;
      int row = c >> 3, k8 = c & 7;
      const float4* pa = reinterpret_cast<const float4*>(
          A + (size_t)(brow + row) * 1024 + kt * 64 + k8 * 8);
      float4 u = pa[0], v = pa[1];
      int4 wa;
      wa.x = pk2(u.x, u.y); wa.y = pk2(u.z, u.w);
      wa.z = pk2(v.x, v.y); wa.w = pk2(v.z, v.w);
      *reinterpret_cast<int4*>(&As[(row << 6) + ((k8 << 3) ^ ((row & 7) << 3))]) = wa;
      const float4* pb = reinterpret_cast<const float4*>(
          W + (size_t)(bcol + row) * 1024 + kt * 64 + k8 * 8);
      float4 s = pb[0], t = pb[1];
      int4 wb;
      wb.x = pk2(s.x, s.y); wb.y = pk2(s.z, s.w);
      wb.z = pk2(t.x, t.y); wb.w = pk2(t.z, t.w);
      *reinterpret_cast<int4*>(&Bs[(row << 6) + ((k8 << 3) ^ ((row & 7) << 3))]) = wb;
    }
    __syncthreads();
#pragma unroll
    for (int kk = 0; kk < 2; ++kk) {
      const int k0 = kk * 32 + ((l >> 4) << 3);
      bf16x8 af[4], bfr[4];
#pragma unroll
      for (int mi = 0; mi < 4; ++mi) {
        int row = (wr << 6) + (mi << 4) + (l & 15);
        af[mi] = *reinterpret_cast<const bf16x8*>(
            &As[(row << 6) + (k0 ^ ((row & 7) << 3))]);
      }
#pragma unroll
      for (int ni = 0; ni < 4; ++ni) {
        int row = (wc << 6) + (ni << 4) + (l & 15);
        bfr[ni] = *reinterpret_cast<const bf16x8*>(
            &Bs[(row << 6) + (k0 ^ ((row & 7) << 3))]);
      }
#pragma unroll
      for (int mi = 0; mi < 4; ++mi)
#pragma unroll
        for (int ni = 0; ni < 4; ++ni)
          acc[mi][ni] = mfma_bf16(af[mi], bfr[ni], acc[mi][ni]);
    }
    __syncthreads();
  }

#pragma unroll
  for (int mi = 0; mi < 4; ++mi)
#pragma unroll
    for (int ni = 0; ni < 4; ++ni)
#pragma unroll
      for (int r = 0; r < 4; ++r) {
        int rowg = brow + (wr << 6) + (mi << 4) + ((l >> 4) << 2) + r;
        int colg = bcol + (wc << 6) + (ni << 4) + (l & 15);
        float val = acc[mi][ni][r];
        if (z == 0) {
          qproj[(size_t)rowg * 1024 + colg] = val;
        } else if (z == 1) {
          kproj[(size_t)rowg * 1024 + colg] = val;
        } else {
          int b = rowg >> 11, n = rowg & 2047;
          int h = colg >> 6, d = colg & 63;
          vb[(((size_t)(b * 16 + h) << 11) + n) * 64 + d] = f2bf(val);
        }
      }
}

// ---------------------------------------------------------------------------
// Per-head LayerNorm (D=64) + optional mup scale, fp32 [R][1024] ->
// bf16 [B,H,L,64].  One wave per row; 4 lanes per head.
// ---------------------------------------------------------------------------
template <int DO_SCALE>
__global__ __launch_bounds__(256, 4)
void ln_head(const float* __restrict__ in, unsigned short* __restrict__ out,
             const float* __restrict__ gw, const float* __restrict__ bw)
{
  const int tid = threadIdx.x;
  const int w = tid >> 6, l = tid & 63;
  const int row = blockIdx.x * 4 + w;      // 0..4095
  const int h = l >> 2, dq = l & 3;        // head, 16-elem quarter
  const float* src = in + (size_t)row * 1024 + h * 64 + dq * 16;
  const float4* p = reinterpret_cast<const float4*>(src);
  float4 a = p[0], b = p[1], c = p[2], d = p[3];
  float x[16] = {a.x, a.y, a.z, a.w, b.x, b.y, b.z, b.w,
                 c.x, c.y, c.z, c.w, d.x, d.y, d.z, d.w};
  float s = 0.f, s2 = 0.f;
#pragma unroll
  for (int j = 0; j < 16; ++j) { s += x[j]; s2 += x[j] * x[j]; }
  s  += __shfl_xor(s, 1);  s  += __shfl_xor(s, 2);
  s2 += __shfl_xor(s2, 1); s2 += __shfl_xor(s2, 2);
  float mean = s * (1.f / 64.f);
  float var  = s2 * (1.f / 64.f) - mean * mean;
  float rstd = rsqrtf(var + 1e-5f);
  float y[16];
#pragma unroll
  for (int j = 0; j < 16; ++j) {
    float t = (x[j] - mean) * rstd * gw[dq * 16 + j] + bw[dq * 16 + j];
    if (DO_SCALE) t *= 0.125f;
    y[j] = t;
  }
  int bb = row >> 11, n = row & 2047;
  unsigned short* dst = out + (((size_t)(bb * 16 + h) << 11) + n) * 64 + dq * 16;
  int4 o0, o1;
  o0.x = pk2(y[0], y[1]);  o0.y = pk2(y[2], y[3]);
  o0.z = pk2(y[4], y[5]);  o0.w = pk2(y[6], y[7]);
  o1.x = pk2(y[8], y[9]);  o1.y = pk2(y[10], y[11]);
  o1.z = pk2(y[12], y[13]); o1.w = pk2(y[14], y[15]);
  *reinterpret_cast<int4*>(dst) = o0;
  *reinterpret_cast<int4*>(dst + 8) = o1;
}

// ---------------------------------------------------------------------------
// Flash attention.  Block = 64 Q-rows of one (b,h); 4 waves, 16 rows each.
// K tile [64][64] and transposed V tile Vt[d][j] in swizzled LDS.
// Online softmax fully per 16-lane row-groups; P via wave-private LDS.
// ---------------------------------------------------------------------------
__global__ __launch_bounds__(256, 3)
void attn_fwd(const unsigned short* __restrict__ Q,
              const unsigned short* __restrict__ K,
              const unsigned short* __restrict__ V,
              unsigned short* __restrict__ O)
{
  __shared__ short Qs[64 * 64];
  __shared__ short Ks[64 * 64];
  __shared__ short Vt[64 * 64];
  __shared__ short Ps[4 * 16 * 64];
  const int tid = threadIdx.x, w = tid >> 6, l = tid & 63;
  const int qt = blockIdx.x, bh = blockIdx.y;
  const unsigned short* Qg = Q + ((size_t)bh * 2048 + qt * 64) * 64;
  const unsigned short* Kg = K + (size_t)bh * 2048 * 64;
  const unsigned short* Vg = V + (size_t)bh * 2048 * 64;

#pragma unroll
  for (int i = 0; i < 2; ++i) {
    int c = i * 256 + tid, row = c >> 3, k8 = c & 7;
    int4 d4 = *reinterpret_cast<const int4*>(Qg + row * 64 + k8 * 8);
    *reinterpret_cast<int4*>(&Qs[(row << 6) + ((k8 << 3) ^ ((row & 7) << 3))]) = d4;
  }
  __syncthreads();
  bf16x8 qa[2];
#pragma unroll
  for (int kk = 0; kk < 2; ++kk) {
    int row = (w << 4) + (l & 15);
    int k0 = kk * 32 + ((l >> 4) << 3);
    qa[kk] = *reinterpret_cast<const bf16x8*>(&Qs[(row << 6) + (k0 ^ ((row & 7) << 3))]);
  }

  const f32x4 zero = {0.f, 0.f, 0.f, 0.f};
  f32x4 oc[4];
#pragma unroll
  for (int f = 0; f < 4; ++f) oc[f] = zero;
  float m[4], ll[4];
#pragma unroll
  for (int r = 0; r < 4; ++r) { m[r] = -1e30f; ll[r] = 0.f; }

  for (int it = 0; it < 32; ++it) {
    const unsigned short* kg = Kg + it * 64 * 64;
    const unsigned short* vg = Vg + it * 64 * 64;
#pragma unroll
    for (int i = 0; i < 2; ++i) {
      int c = i * 256 + tid, row = c >> 3, k8 = c & 7;
      int4 d4 = *reinterpret_cast<const int4*>(kg + row * 64 + k8 * 8);
      *reinterpret_cast<int4*>(&Ks[(row << 6) + ((k8 << 3) ^ ((row & 7) << 3))]) = d4;
    }
#pragma unroll
    for (int i = 0; i < 2; ++i) {
      int c = i * 256 + tid, j = c >> 3, d0 = (c & 7) * 8;
      int4 d4 = *reinterpret_cast<const int4*>(vg + j * 64 + d0);
      unsigned uu[4] = {(unsigned)d4.x, (unsigned)d4.y, (unsigned)d4.z, (unsigned)d4.w};
#pragma unroll
      for (int e = 0; e < 8; ++e) {
        int d = d0 + e;
        unsigned short val = (unsigned short)((uu[e >> 1] >> ((e & 1) * 16)) & 0xffffu);
        Vt[(d << 6) + (j ^ ((d & 7) << 3))] = (short)val;
      }
    }
    __syncthreads();

    f32x4 s[4];
#pragma unroll
    for (int ni = 0; ni < 4; ++ni) s[ni] = zero;
#pragma unroll
    for (int kk = 0; kk < 2; ++kk) {
      int k0 = kk * 32 + ((l >> 4) << 3);
#pragma unroll
      for (int ni = 0; ni < 4; ++ni) {
        int row = (ni << 4) + (l & 15);
        bf16x8 kb = *reinterpret_cast<const bf16x8*>(
            &Ks[(row << 6) + (k0 ^ ((row & 7) << 3))]);
        s[ni] = mfma_bf16(qa[kk], kb, s[ni]);
      }
    }

    float pm[4], al[4], rs[4];
#pragma unroll
    for (int r = 0; r < 4; ++r)
      pm[r] = fmaxf(fmaxf(s[0][r], s[1][r]), fmaxf(s[2][r], s[3][r]));
#pragma unroll
    for (int off = 1; off < 16; off <<= 1)
#pragma unroll
      for (int r = 0; r < 4; ++r)
        pm[r] = fmaxf(pm[r], __shfl_xor(pm[r], off));
#pragma unroll
    for (int r = 0; r < 4; ++r) {
      float mn = fmaxf(m[r], pm[r]);
      al[r] = __expf(m[r] - mn);
      m[r] = mn;
    }
#pragma unroll
    for (int ni = 0; ni < 4; ++ni)
#pragma unroll
      for (int r = 0; r < 4; ++r)
        s[ni][r] = __expf(s[ni][r] - m[r]);
#pragma unroll
    for (int r = 0; r < 4; ++r)
      rs[r] = (s[0][r] + s[1][r]) + (s[2][r] + s[3][r]);
#pragma unroll
    for (int off = 1; off < 16; off <<= 1)
#pragma unroll
      for (int r = 0; r < 4; ++r)
        rs[r] += __shfl_xor(rs[r], off);
#pragma unroll
    for (int r = 0; r < 4; ++r)
      ll[r] = ll[r] * al[r] + rs[r];
#pragma unroll
    for (int f = 0; f < 4; ++f)
#pragma unroll
      for (int r = 0; r < 4; ++r)
        oc[f][r] *= al[r];

    short* Pw = &Ps[w * 1024];
#pragma unroll
    for (int ni = 0; ni < 4; ++ni)
#pragma unroll
      for (int r = 0; r < 4; ++r) {
        int prow = ((l >> 4) << 2) + r;
        int pcol = (ni << 4) + (l & 15);
        Pw[(prow << 6) + (pcol ^ ((prow & 7) << 3))] = (short)f2bf(s[ni][r]);
      }
    bf16x8 pa[2];
#pragma unroll
    for (int kk = 0; kk < 2; ++kk) {
      int prow = l & 15;
      int j0 = kk * 32 + ((l >> 4) << 3);
      pa[kk] = *reinterpret_cast<const bf16x8*>(
          &Pw[(prow << 6) + (j0 ^ ((prow & 7) << 3))]);
    }
#pragma unroll
    for (int kk = 0; kk < 2; ++kk) {
      int j0 = kk * 32 + ((l >> 4) << 3);
#pragma unroll
      for (int f = 0; f < 4; ++f) {
        int d = (f << 4) + (l & 15);
        bf16x8 vbf = *reinterpret_cast<const bf16x8*>(
            &Vt[(d << 6) + (j0 ^ ((d & 7) << 3))]);
        oc[f] = mfma_bf16(pa[kk], vbf, oc[f]);
      }
    }
    __syncthreads();
  }

  unsigned short* Og = O + ((size_t)bh * 2048 + qt * 64 + (w << 4)) * 64;
  float inv[4];
#pragma unroll
  for (int r = 0; r < 4; ++r) inv[r] = 1.f / ll[r];
#pragma unroll
  for (int f = 0; f < 4; ++f)
#pragma unroll
    for (int r = 0; r < 4; ++r) {
      int prow = ((l >> 4) << 2) + r;
      Og[prow * 64 + (f << 4) + (l & 15)] = f2bf(oc[f][r] * inv[r]);
    }
}

// ---------------------------------------------------------------------------
// Output projection: out[r][o] = sum_c Ocat[r][c] * Wp[o][c] + bp[o]
// Ocat row r=(b,n), col c=h*64+d comes from ob[B,H,N,D]; kt == head.
// ---------------------------------------------------------------------------
__global__ __launch_bounds__(256, 2)
void gemm_out(const unsigned short* __restrict__ ob, const float* __restrict__ Wp,
              const float* __restrict__ bp, float* __restrict__ out)
{
  __shared__ short As[128 * 64];
  __shared__ short Bs[128 * 64];
  const int tid = threadIdx.x;
  const int l = tid & 63, w = tid >> 6;
  const int wr = w >> 1, wc = w & 1;
  const int brow = blockIdx.y * 128, bcol = blockIdx.x * 128;

  const f32x4 zero = {0.f, 0.f, 0.f, 0.f};
  f32x4 acc[4][4];
#pragma unroll
  for (int mi = 0; mi < 4; ++mi)
#pragma unroll
    for (int ni = 0; ni < 4; ++ni) acc[mi][ni] = zero;

  for (int kt = 0; kt < 16; ++kt) {
#pragma unroll
    for (int i = 0; i < 4; ++i) {
      int c = i * 256 + tid;
      int row = c >> 3, k8 = c & 7;
      int rowg = brow + row;
      int b = rowg >> 11, n = rowg & 2047;
      int4 d4 = *reinterpret_cast<const int4*>(
          ob + (((size_t)(b * 16 + kt) << 11) + n) * 64 + k8 * 8);
      *reinterpret_cast<int4*>(&As[(row << 6) + ((k8 << 3) ^ ((row & 7) << 3))]) = d4;
      const float4* pb = reinterpret_cast<const float4*>(
          Wp + (size_t)(bcol + row) * 1024 + kt * 64 + k8 * 8);
      float4 s = pb[0], t = pb[1];
      int4 wb;
      wb.x = pk2(s.x, s.y); wb.y = pk2(s.z, s.w);
      wb.z = pk2(t.x, t.y); wb.w = pk2(t.z, t.w);
      *reinterpret_cast<int4*>(&Bs[(row << 6) + ((k8 << 3) ^ ((row & 7) << 3))]) = wb;
    }
    __syncthreads();
#pragma unroll
    for (int kk = 0; kk < 2; ++kk) {
      const int k0 = kk * 32 + ((l >> 4) << 3);
      bf16x8 af[4], bfr[4];
#pragma unroll
      for (int mi = 0; mi < 4; ++mi) {
        int row = (wr << 6) + (mi << 4) + (l & 15);
        af[mi] = *reinterpret_cast<const bf16x8*>(
            &As[(row << 6) + (k0 ^ ((row & 7) << 3))]);
      }
#pragma unroll
      for (int ni = 0; ni < 4; ++ni) {
        int row = (wc << 6) + (ni << 4) + (l & 15);
        bfr[ni] = *reinterpret_cast<const bf16x8*>(
            &Bs[(row << 6) + (k0 ^ ((row & 7) << 3))]);
      }
#pragma unroll
      for (int mi = 0; mi < 4; ++mi)
#pragma unroll
        for (int ni = 0; ni < 4; ++ni)
          acc[mi][ni] = mfma_bf16(af[mi], bfr[ni], acc[mi][ni]);
    }
    __syncthreads();
  }

  float bias[4];
#pragma unroll
  for (int ni = 0; ni < 4; ++ni)
    bias[ni] = bp[bcol + (wc << 6) + (ni << 4) + (l & 15)];
#pragma unroll
  for (int mi = 0; mi < 4; ++mi)
#pragma unroll
    for (int ni = 0; ni < 4; ++ni)
#pragma unroll
      for (int r = 0; r < 4; ++r) {
        int rowg = brow + (wr << 6) + (mi << 4) + ((l >> 4) << 2) + r;
        int colg = bcol + (wc << 6) + (ni << 4) + (l & 15);
        out[(size_t)rowg * 1024 + colg] = acc[mi][ni][r] + bias[ni];
      }
}

// ---------------------------------------------------------------------------
extern "C" void kernel_launch(void* const* d_in, const int* in_sizes, int n_in,
                              void* d_out, int out_size, void* d_ws, size_t ws_size,
                              hipStream_t stream)
{
  const float* x1 = (const float*)d_in[0];
  const float* x2 = (const float*)d_in[1];
  const float* Wq = (const float*)d_in[2];
  const float* Wk = (const float*)d_in[3];
  const float* Wv = (const float*)d_in[4];
  const float* Wp = (const float*)d_in[5];
  const float* bp = (const float*)d_in[6];
  const float* lg = (const float*)d_in[7];
  const float* lb = (const float*)d_in[8];

  char* wsb = (char*)d_ws;
  float* qproj = (float*)wsb;                          // 16 MiB
  float* kproj = (float*)(wsb + 16777216);             // 16 MiB
  unsigned short* qb = (unsigned short*)(wsb + 33554432);  // 8 MiB
  unsigned short* kb = qb + 4194304;                   // 8 MiB
  unsigned short* vb = kb + 4194304;                   // 8 MiB
  unsigned short* obuf = vb + 4194304;                 // 8 MiB  (total 64 MiB)
  float* out = (float*)d_out;

  gemm_qkv<<<dim3(8, 32, 3), 256, 0, stream>>>(x1, x2, Wq, Wk, Wv, qproj, kproj, vb);
  ln_head<1><<<1024, 256, 0, stream>>>(qproj, qb, lg, lb);
  ln_head<0><<<1024, 256, 0, stream>>>(kproj, kb, lg, lb);
  attn_fwd<<<dim3(32, 32), 256, 0, stream>>>(qb, kb, vb, obuf);
  gemm_out<<<dim3(8, 32), 256, 0, stream>>>(obuf, Wp, bp, out);
}

// Round 2
// 179.725 us; speedup vs baseline: 1.5356x; 1.5356x over previous
//
#include <hip/hip_runtime.h>

#define DEV static __device__ __forceinline__

using bf16x8 = __attribute__((ext_vector_type(8))) short;
using f32x4  = __attribute__((ext_vector_type(4))) float;
using f32x16 = __attribute__((ext_vector_type(16))) float;

// fp32 -> bf16 bits, round-to-nearest-even (inputs are finite)
DEV unsigned short f2bf(float f) {
  union { float f; unsigned u; } v; v.f = f;
  return (unsigned short)((v.u + 0x7fffu + ((v.u >> 16) & 1u)) >> 16);
}
DEV unsigned pk2(float lo, float hi) {
  return (unsigned)f2bf(lo) | ((unsigned)f2bf(hi) << 16);
}
DEV bf16x8 mk8(unsigned a, unsigned b, unsigned c, unsigned d) {
  union { unsigned u[4]; bf16x8 v; } t;
  t.u[0] = a; t.u[1] = b; t.u[2] = c; t.u[3] = d;
  return t.v;
}
DEV f32x4 mfma16(bf16x8 a, bf16x8 b, f32x4 c) {
  return __builtin_amdgcn_mfma_f32_16x16x32_bf16(a, b, c, 0, 0, 0);
}
DEV f32x16 mfma32(bf16x8 a, bf16x8 b, f32x16 c) {
  return __builtin_amdgcn_mfma_f32_32x32x16_bf16(a, b, c, 0, 0, 0);
}
DEV f32x16 zero16() {
  f32x16 z;
#pragma unroll
  for (int i = 0; i < 16; ++i) z[i] = 0.f;
  return z;
}

// ---------------------------------------------------------------------------
// Fused QKV projection GEMM.  C[r][o] = sum_k A[r][k] * W[o][k]
// z=0 -> qproj fp32; z=1 -> kproj fp32; z=2 -> V^T bf16 [B,H,D,M].
// ---------------------------------------------------------------------------
__global__ __launch_bounds__(256, 2)
void gemm_qkv(const float* __restrict__ x1, const float* __restrict__ x2,
              const float* __restrict__ Wq, const float* __restrict__ Wk,
              const float* __restrict__ Wv,
              float* __restrict__ qproj, float* __restrict__ kproj,
              unsigned short* __restrict__ vtb)
{
  __shared__ short As[128 * 64];
  __shared__ short Bs[128 * 64];
  const int tid = threadIdx.x;
  const int l = tid & 63, w = tid >> 6;
  const int wr = w >> 1, wc = w & 1;
  const int z = blockIdx.z;
  const float* A = (z == 0) ? x1 : x2;
  const float* W = (z == 0) ? Wq : (z == 1 ? Wk : Wv);
  const int brow = blockIdx.y * 128, bcol = blockIdx.x * 128;

  const f32x4 zero = {0.f, 0.f, 0.f, 0.f};
  f32x4 acc[4][4];
#pragma unroll
  for (int mi = 0; mi < 4; ++mi)
#pragma unroll
    for (int ni = 0; ni < 4; ++ni) acc[mi][ni] = zero;

  for (int kt = 0; kt < 16; ++kt) {
#pragma unroll
    for (int i = 0; i < 4; ++i) {
      int c = i * 256 + tid;
      int row = c >> 3, k8 = c & 7;
      const float4* pa = reinterpret_cast<const float4*>(
          A + (size_t)(brow + row) * 1024 + kt * 64 + k8 * 8);
      float4 u = pa[0], v = pa[1];
      int4 wa;
      wa.x = pk2(u.x, u.y); wa.y = pk2(u.z, u.w);
      wa.z = pk2(v.x, v.y); wa.w = pk2(v.z, v.w);
      *reinterpret_cast<int4*>(&As[(row << 6) + ((k8 << 3) ^ ((row & 7) << 3))]) = wa;
      const float4* pb = reinterpret_cast<const float4*>(
          W + (size_t)(bcol + row) * 1024 + kt * 64 + k8 * 8);
      float4 s = pb[0], t = pb[1];
      int4 wb;
      wb.x = pk2(s.x, s.y); wb.y = pk2(s.z, s.w);
      wb.z = pk2(t.x, t.y); wb.w = pk2(t.z, t.w);
      *reinterpret_cast<int4*>(&Bs[(row << 6) + ((k8 << 3) ^ ((row & 7) << 3))]) = wb;
    }
    __syncthreads();
#pragma unroll
    for (int kk = 0; kk < 2; ++kk) {
      const int k0 = kk * 32 + ((l >> 4) << 3);
      bf16x8 af[4], bfr[4];
#pragma unroll
      for (int mi = 0; mi < 4; ++mi) {
        int row = (wr << 6) + (mi << 4) + (l & 15);
        af[mi] = *reinterpret_cast<const bf16x8*>(
            &As[(row << 6) + (k0 ^ ((row & 7) << 3))]);
      }
#pragma unroll
      for (int ni = 0; ni < 4; ++ni) {
        int row = (wc << 6) + (ni << 4) + (l & 15);
        bfr[ni] = *reinterpret_cast<const bf16x8*>(
            &Bs[(row << 6) + (k0 ^ ((row & 7) << 3))]);
      }
#pragma unroll
      for (int mi = 0; mi < 4; ++mi)
#pragma unroll
        for (int ni = 0; ni < 4; ++ni)
          acc[mi][ni] = mfma16(af[mi], bfr[ni], acc[mi][ni]);
    }
    __syncthreads();
  }

  if (z < 2) {
    float* dst = (z == 0) ? qproj : kproj;
#pragma unroll
    for (int mi = 0; mi < 4; ++mi)
#pragma unroll
      for (int ni = 0; ni < 4; ++ni)
#pragma unroll
        for (int r = 0; r < 4; ++r) {
          int rowg = brow + (wr << 6) + (mi << 4) + ((l >> 4) << 2) + r;
          int colg = bcol + (wc << 6) + (ni << 4) + (l & 15);
          dst[(size_t)rowg * 1024 + colg] = acc[mi][ni][r];
        }
  } else {
    // V^T: vtb[((b*16+h)*64+d)*2048 + n], 4 consecutive n packed
    const int bb = brow >> 11;
    const int nblk = brow & 2047;
#pragma unroll
    for (int mi = 0; mi < 4; ++mi)
#pragma unroll
      for (int ni = 0; ni < 4; ++ni) {
        int n0 = nblk + (wr << 6) + (mi << 4) + ((l >> 4) << 2);
        int colg = bcol + (wc << 6) + (ni << 4) + (l & 15);
        int h = colg >> 6, d = colg & 63;
        ushort4 u;
        u.x = f2bf(acc[mi][ni][0]); u.y = f2bf(acc[mi][ni][1]);
        u.z = f2bf(acc[mi][ni][2]); u.w = f2bf(acc[mi][ni][3]);
        *reinterpret_cast<ushort4*>(
            &vtb[((size_t)(bb * 16 + h) * 64 + d) * 2048 + n0]) = u;
      }
  }
}

// ---------------------------------------------------------------------------
// Per-head LayerNorm (D=64) + optional mup scale, fp32 [R][1024] ->
// bf16 [B,H,L,64].  One wave per row; 4 lanes per head.
// ---------------------------------------------------------------------------
template <int DO_SCALE>
__global__ __launch_bounds__(256, 4)
void ln_head(const float* __restrict__ in, unsigned short* __restrict__ out,
             const float* __restrict__ gw, const float* __restrict__ bw)
{
  const int tid = threadIdx.x;
  const int w = tid >> 6, l = tid & 63;
  const int row = blockIdx.x * 4 + w;      // 0..4095
  const int h = l >> 2, dq = l & 3;        // head, 16-elem quarter
  const float* src = in + (size_t)row * 1024 + h * 64 + dq * 16;
  const float4* p = reinterpret_cast<const float4*>(src);
  float4 a = p[0], b = p[1], c = p[2], d = p[3];
  float x[16] = {a.x, a.y, a.z, a.w, b.x, b.y, b.z, b.w,
                 c.x, c.y, c.z, c.w, d.x, d.y, d.z, d.w};
  float s = 0.f, s2 = 0.f;
#pragma unroll
  for (int j = 0; j < 16; ++j) { s += x[j]; s2 += x[j] * x[j]; }
  s  += __shfl_xor(s, 1);  s  += __shfl_xor(s, 2);
  s2 += __shfl_xor(s2, 1); s2 += __shfl_xor(s2, 2);
  float mean = s * (1.f / 64.f);
  float var  = s2 * (1.f / 64.f) - mean * mean;
  float rstd = rsqrtf(var + 1e-5f);
  float y[16];
#pragma unroll
  for (int j = 0; j < 16; ++j) {
    float t = (x[j] - mean) * rstd * gw[dq * 16 + j] + bw[dq * 16 + j];
    if (DO_SCALE) t *= 0.125f;
    y[j] = t;
  }
  int bb = row >> 11, n = row & 2047;
  unsigned short* dst = out + (((size_t)(bb * 16 + h) << 11) + n) * 64 + dq * 16;
  int4 o0, o1;
  o0.x = pk2(y[0], y[1]);  o0.y = pk2(y[2], y[3]);
  o0.z = pk2(y[4], y[5]);  o0.w = pk2(y[6], y[7]);
  o1.x = pk2(y[8], y[9]);  o1.y = pk2(y[10], y[11]);
  o1.z = pk2(y[12], y[13]); o1.w = pk2(y[14], y[15]);
  *reinterpret_cast<int4*>(dst) = o0;
  *reinterpret_cast<int4*>(dst + 8) = o1;
}

// ---------------------------------------------------------------------------
// Flash attention, swapped-QK^T 32x32 structure.
// Block = 128 Q-rows of one (b,h); 4 waves x 32 rows. KVBLK = 64.
// S^T = mfma32(K, Q): lane holds P[q=l&31][j=crow(r,hi)] in 2x16 regs.
// In-register softmax (+1 shfl_xor(32)); defer-max rescale (THR=8).
// P repacked to MFMA A-frags via pk2 + shfl_xor(32) + cndmask.
// V^T tiles staged from precomputed vtb (no transpose in-kernel).
// ---------------------------------------------------------------------------
__global__ __launch_bounds__(256, 2)
void attn_fwd(const unsigned short* __restrict__ Q,
              const unsigned short* __restrict__ K,
              const unsigned short* __restrict__ Vt,
              unsigned short* __restrict__ O)
{
  __shared__ short Ks[64 * 64];
  __shared__ short Vs[64 * 64];
  const int tid = threadIdx.x, w = tid >> 6, l = tid & 63;
  const int lo5 = l & 31, hi = l >> 5;
  const int bh = blockIdx.y;
  const int qbase = blockIdx.x * 128 + w * 32;
  const unsigned short* Qg = Q + ((size_t)bh * 2048 + qbase) * 64;
  const unsigned short* Kg = K + (size_t)bh * 2048 * 64;
  const unsigned short* Vg = Vt + (size_t)bh * 64 * 2048;

  // Q B-fragments hoisted: n=q=l&31, k=d=16*ks+8*hi
  bf16x8 qf[4];
#pragma unroll
  for (int ks = 0; ks < 4; ++ks)
    qf[ks] = *reinterpret_cast<const bf16x8*>(Qg + lo5 * 64 + ks * 16 + hi * 8);

  f32x16 oc0 = zero16(), oc1 = zero16();
  float m = -1e30f, lsum = 0.f;

  for (int it = 0; it < 32; ++it) {
    // stage K tile [64 j][64 d] and Vt tile [64 d][64 j], swizzled
#pragma unroll
    for (int i = 0; i < 2; ++i) {
      int cc = i * 256 + tid, row = cc >> 3, c8 = cc & 7;
      int4 dk = *reinterpret_cast<const int4*>(Kg + (it * 64 + row) * 64 + c8 * 8);
      *reinterpret_cast<int4*>(&Ks[(row << 6) + ((c8 << 3) ^ ((row & 7) << 3))]) = dk;
      int4 dv = *reinterpret_cast<const int4*>(Vg + (size_t)row * 2048 + it * 64 + c8 * 8);
      *reinterpret_cast<int4*>(&Vs[(row << 6) + ((c8 << 3) ^ ((row & 7) << 3))]) = dv;
    }
    __syncthreads();

    // QK^T (swapped): s = mfma(A=K, B=Q) -> S[q=col][j=row]
    f32x16 s0 = zero16(), s1 = zero16();
#pragma unroll
    for (int ks = 0; ks < 4; ++ks) {
      const int colc = (16 * ks + 8 * hi) ^ ((lo5 & 7) << 3);
      bf16x8 k0 = *reinterpret_cast<const bf16x8*>(&Ks[(lo5 << 6) + colc]);
      s0 = mfma32(k0, qf[ks], s0);
      bf16x8 k1 = *reinterpret_cast<const bf16x8*>(&Ks[((32 + lo5) << 6) + colc]);
      s1 = mfma32(k1, qf[ks], s1);
    }

    // online softmax: in-register max + one cross-half exchange
    float pm = s0[0];
#pragma unroll
    for (int r = 1; r < 16; ++r) pm = fmaxf(pm, s0[r]);
#pragma unroll
    for (int r = 0; r < 16; ++r) pm = fmaxf(pm, s1[r]);
    pm = fmaxf(pm, __shfl_xor(pm, 32));
    if (!__all(pm <= m + 8.f)) {
      float mn = fmaxf(m, pm);
      float al = __expf(m - mn);
      m = mn; lsum *= al;
#pragma unroll
      for (int r = 0; r < 16; ++r) {
        float ar = __shfl(al, (r & 3) + 8 * (r >> 2) + 4 * hi);
        oc0[r] *= ar; oc1[r] *= ar;
      }
    }

    // exp + repack to A-frags + PV, per 32-j subchunk
    auto pvsub = [&](const f32x16& sv, int jbase) {
      float p0[16];
#pragma unroll
      for (int r = 0; r < 16; ++r) { p0[r] = __expf(sv[r] - m); lsum += p0[r]; }
#pragma unroll
      for (int f = 0; f < 2; ++f) {
        unsigned x  = pk2(p0[8 * f + 0], p0[8 * f + 1]);
        unsigned zz = pk2(p0[8 * f + 2], p0[8 * f + 3]);
        unsigned y  = pk2(p0[8 * f + 4], p0[8 * f + 5]);
        unsigned ww = pk2(p0[8 * f + 6], p0[8 * f + 7]);
        unsigned xs = (unsigned)__shfl_xor((int)x, 32);
        unsigned zs = (unsigned)__shfl_xor((int)zz, 32);
        unsigned ys = (unsigned)__shfl_xor((int)y, 32);
        unsigned ws = (unsigned)__shfl_xor((int)ww, 32);
        unsigned a0 = hi ? ys : x;
        unsigned a1 = hi ? ws : zz;
        unsigned a2 = hi ? y  : xs;
        unsigned a3 = hi ? ww : zs;
        bf16x8 pa = mk8(a0, a1, a2, a3);
        const int colc = (jbase + 16 * f + 8 * hi);
        bf16x8 v0 = *reinterpret_cast<const bf16x8*>(
            &Vs[(lo5 << 6) + (colc ^ ((lo5 & 7) << 3))]);
        oc0 = mfma32(pa, v0, oc0);
        bf16x8 v1 = *reinterpret_cast<const bf16x8*>(
            &Vs[((32 + lo5) << 6) + (colc ^ ((lo5 & 7) << 3))]);
        oc1 = mfma32(pa, v1, oc1);
      }
    };
    pvsub(s0, 0);
    pvsub(s1, 32);
    __syncthreads();
  }

  // epilogue: combine partial sums across lane halves, normalize, store
  lsum += __shfl_xor(lsum, 32);
  float inv = 1.f / lsum;
  unsigned short* Og = O + ((size_t)bh * 2048 + qbase) * 64;
#pragma unroll
  for (int r = 0; r < 16; ++r) {
    int qrow = (r & 3) + 8 * (r >> 2) + 4 * hi;
    float ir = __shfl(inv, qrow);
    Og[qrow * 64 + lo5]      = f2bf(oc0[r] * ir);
    Og[qrow * 64 + 32 + lo5] = f2bf(oc1[r] * ir);
  }
}

// ---------------------------------------------------------------------------
// Output projection: out[r][o] = sum_c Ocat[r][c] * Wp[o][c] + bp[o]
// ---------------------------------------------------------------------------
__global__ __launch_bounds__(256, 2)
void gemm_out(const unsigned short* __restrict__ ob, const float* __restrict__ Wp,
              const float* __restrict__ bp, float* __restrict__ out)
{
  __shared__ short As[128 * 64];
  __shared__ short Bs[128 * 64];
  const int tid = threadIdx.x;
  const int l = tid & 63, w = tid >> 6;
  const int wr = w >> 1, wc = w & 1;
  const int brow = blockIdx.y * 128, bcol = blockIdx.x * 128;

  const f32x4 zero = {0.f, 0.f, 0.f, 0.f};
  f32x4 acc[4][4];
#pragma unroll
  for (int mi = 0; mi < 4; ++mi)
#pragma unroll
    for (int ni = 0; ni < 4; ++ni) acc[mi][ni] = zero;

  for (int kt = 0; kt < 16; ++kt) {
#pragma unroll
    for (int i = 0; i < 4; ++i) {
      int c = i * 256 + tid;
      int row = c >> 3, k8 = c & 7;
      int rowg = brow + row;
      int b = rowg >> 11, n = rowg & 2047;
      int4 d4 = *reinterpret_cast<const int4*>(
          ob + (((size_t)(b * 16 + kt) << 11) + n) * 64 + k8 * 8);
      *reinterpret_cast<int4*>(&As[(row << 6) + ((k8 << 3) ^ ((row & 7) << 3))]) = d4;
      const float4* pb = reinterpret_cast<const float4*>(
          Wp + (size_t)(bcol + row) * 1024 + kt * 64 + k8 * 8);
      float4 s = pb[0], t = pb[1];
      int4 wb;
      wb.x = pk2(s.x, s.y); wb.y = pk2(s.z, s.w);
      wb.z = pk2(t.x, t.y); wb.w = pk2(t.z, t.w);
      *reinterpret_cast<int4*>(&Bs[(row << 6) + ((k8 << 3) ^ ((row & 7) << 3))]) = wb;
    }
    __syncthreads();
#pragma unroll
    for (int kk = 0; kk < 2; ++kk) {
      const int k0 = kk * 32 + ((l >> 4) << 3);
      bf16x8 af[4], bfr[4];
#pragma unroll
      for (int mi = 0; mi < 4; ++mi) {
        int row = (wr << 6) + (mi << 4) + (l & 15);
        af[mi] = *reinterpret_cast<const bf16x8*>(
            &As[(row << 6) + (k0 ^ ((row & 7) << 3))]);
      }
#pragma unroll
      for (int ni = 0; ni < 4; ++ni) {
        int row = (wc << 6) + (ni << 4) + (l & 15);
        bfr[ni] = *reinterpret_cast<const bf16x8*>(
            &Bs[(row << 6) + (k0 ^ ((row & 7) << 3))]);
      }
#pragma unroll
      for (int mi = 0; mi < 4; ++mi)
#pragma unroll
        for (int ni = 0; ni < 4; ++ni)
          acc[mi][ni] = mfma16(af[mi], bfr[ni], acc[mi][ni]);
    }
    __syncthreads();
  }

  float bias[4];
#pragma unroll
  for (int ni = 0; ni < 4; ++ni)
    bias[ni] = bp[bcol + (wc << 6) + (ni << 4) + (l & 15)];
#pragma unroll
  for (int mi = 0; mi < 4; ++mi)
#pragma unroll
    for (int ni = 0; ni < 4; ++ni)
#pragma unroll
      for (int r = 0; r < 4; ++r) {
        int rowg = brow + (wr << 6) + (mi << 4) + ((l >> 4) << 2) + r;
        int colg = bcol + (wc << 6) + (ni << 4) + (l & 15);
        out[(size_t)rowg * 1024 + colg] = acc[mi][ni][r] + bias[ni];
      }
}

// ---------------------------------------------------------------------------
extern "C" void kernel_launch(void* const* d_in, const int* in_sizes, int n_in,
                              void* d_out, int out_size, void* d_ws, size_t ws_size,
                              hipStream_t stream)
{
  const float* x1 = (const float*)d_in[0];
  const float* x2 = (const float*)d_in[1];
  const float* Wq = (const float*)d_in[2];
  const float* Wk = (const float*)d_in[3];
  const float* Wv = (const float*)d_in[4];
  const float* Wp = (const float*)d_in[5];
  const float* bp = (const float*)d_in[6];
  const float* lg = (const float*)d_in[7];
  const float* lb = (const float*)d_in[8];

  char* wsb = (char*)d_ws;
  float* qproj = (float*)wsb;                              // 16 MiB
  float* kproj = (float*)(wsb + 16777216);                 // 16 MiB
  unsigned short* qb  = (unsigned short*)(wsb + 33554432); // 8 MiB
  unsigned short* kb  = qb + 4194304;                      // 8 MiB
  unsigned short* vtb = kb + 4194304;                      // 8 MiB (V^T)
  unsigned short* obuf = vtb + 4194304;                    // 8 MiB
  float* out = (float*)d_out;

  gemm_qkv<<<dim3(8, 32, 3), 256, 0, stream>>>(x1, x2, Wq, Wk, Wv, qproj, kproj, vtb);
  ln_head<1><<<1024, 256, 0, stream>>>(qproj, qb, lg, lb);
  ln_head<0><<<1024, 256, 0, stream>>>(kproj, kb, lg, lb);
  attn_fwd<<<dim3(16, 32), 256, 0, stream>>>(qb, kb, vtb, obuf);
  gemm_out<<<dim3(8, 32), 256, 0, stream>>>(obuf, Wp, bp, out);
}

// Round 3
// 157.296 us; speedup vs baseline: 1.7545x; 1.1426x over previous
//
#include <hip/hip_runtime.h>

#define DEV static __device__ __forceinline__

using bf16x8 = __attribute__((ext_vector_type(8))) short;
using f32x4  = __attribute__((ext_vector_type(4))) float;
using f32x16 = __attribute__((ext_vector_type(16))) float;

DEV unsigned short f2bf(float f) {
  union { float f; unsigned u; } v; v.f = f;
  return (unsigned short)((v.u + 0x7fffu + ((v.u >> 16) & 1u)) >> 16);
}
DEV unsigned pk2(float lo, float hi) {
  return (unsigned)f2bf(lo) | ((unsigned)f2bf(hi) << 16);
}
DEV bf16x8 mk8(unsigned a, unsigned b, unsigned c, unsigned d) {
  union { unsigned u[4]; bf16x8 v; } t;
  t.u[0] = a; t.u[1] = b; t.u[2] = c; t.u[3] = d;
  return t.v;
}
DEV f32x4 mfma16(bf16x8 a, bf16x8 b, f32x4 c) {
  return __builtin_amdgcn_mfma_f32_16x16x32_bf16(a, b, c, 0, 0, 0);
}
DEV f32x16 mfma32(bf16x8 a, bf16x8 b, f32x16 c) {
  return __builtin_amdgcn_mfma_f32_32x32x16_bf16(a, b, c, 0, 0, 0);
}
DEV f32x16 zero16() {
  f32x16 z;
#pragma unroll
  for (int i = 0; i < 16; ++i) z[i] = 0.f;
  return z;
}

typedef const __attribute__((address_space(1))) unsigned int* gas1;
typedef __attribute__((address_space(3))) unsigned int* las3;
// async global->LDS, 16B per lane; LDS dest = wave-uniform base + lane*16
DEV void gl16(const void* g, void* l) {
  __builtin_amdgcn_global_load_lds((gas1)g, (las3)l, 16, 0, 0);
}

// ---------------------------------------------------------------------------
// fp32 -> bf16 pre-convert: x1(4M) x2(4M) Wq Wk Wv Wp (1M each) -> one 12M
// ushort region.  8 elems/thread, memory-bound.
// ---------------------------------------------------------------------------
__global__ __launch_bounds__(256, 8)
void conv_bf16(const float* __restrict__ x1, const float* __restrict__ x2,
               const float* __restrict__ Wq, const float* __restrict__ Wk,
               const float* __restrict__ Wv, const float* __restrict__ Wp,
               unsigned short* __restrict__ o)
{
  size_t e = ((size_t)blockIdx.x * 256 + threadIdx.x) * 8;
  const float* s; size_t off;
  if (e < 4194304u)       { s = x1; off = e; }
  else if (e < 8388608u)  { s = x2; off = e - 4194304u; }
  else if (e < 9437184u)  { s = Wq; off = e - 8388608u; }
  else if (e < 10485760u) { s = Wk; off = e - 9437184u; }
  else if (e < 11534336u) { s = Wv; off = e - 10485760u; }
  else                    { s = Wp; off = e - 11534336u; }
  const float4* p = reinterpret_cast<const float4*>(s + off);
  float4 a = p[0], b = p[1];
  int4 r;
  r.x = pk2(a.x, a.y); r.y = pk2(a.z, a.w);
  r.z = pk2(b.x, b.y); r.w = pk2(b.z, b.w);
  *reinterpret_cast<int4*>(o + e) = r;
}

// ---------------------------------------------------------------------------
// Fused QKV GEMM (m97 structure): C[r][o] = sum_k A[r][k] * W[o][k], bf16 in.
// 128x128 tile, BK=64, global_load_lds(16B) -> linear LDS, 4 waves 2x2.
// z=0 -> qproj fp32; z=1 -> kproj fp32; z=2 -> V^T bf16 [B,H,D,M].
// ---------------------------------------------------------------------------
__global__ __launch_bounds__(256, 2)
void gemm_qkv_bf(const unsigned short* __restrict__ xb,
                 float* __restrict__ qproj, float* __restrict__ kproj,
                 unsigned short* __restrict__ vtb)
{
  __shared__ short As[128 * 64];
  __shared__ short Bs[128 * 64];
  const int tid = threadIdx.x;
  const int l = tid & 63, w = tid >> 6;
  const int wr = w >> 1, wc = w & 1;
  const int z = blockIdx.z;
  const unsigned short* A = (z == 0) ? xb : (xb + 4194304);
  const unsigned short* W = xb + 8388608 + (size_t)z * 1048576;
  const int brow = blockIdx.y * 128, bcol = blockIdx.x * 128;

  const f32x4 zero = {0.f, 0.f, 0.f, 0.f};
  f32x4 acc[4][4];
#pragma unroll
  for (int mi = 0; mi < 4; ++mi)
#pragma unroll
    for (int ni = 0; ni < 4; ++ni) acc[mi][ni] = zero;

  const int srow = w * 32 + (l >> 3);        // staging row base (this wave)
  const int scol = (l & 7) * 8;              // staging col (elems)

  for (int kt = 0; kt < 16; ++kt) {
    const unsigned short* ga = A + (size_t)(brow + srow) * 1024 + kt * 64 + scol;
    const unsigned short* gb = W + (size_t)(bcol + srow) * 1024 + kt * 64 + scol;
#pragma unroll
    for (int i = 0; i < 4; ++i) {
      gl16(ga + (size_t)i * 8 * 1024, &As[(w * 32 + i * 8) * 64]);
      gl16(gb + (size_t)i * 8 * 1024, &Bs[(w * 32 + i * 8) * 64]);
    }
    __syncthreads();
#pragma unroll
    for (int kk = 0; kk < 2; ++kk) {
      const int k0 = kk * 32 + ((l >> 4) << 3);
      bf16x8 af[4], bfr[4];
#pragma unroll
      for (int mi = 0; mi < 4; ++mi)
        af[mi] = *reinterpret_cast<const bf16x8*>(
            &As[((wr << 6) + (mi << 4) + (l & 15)) * 64 + k0]);
#pragma unroll
      for (int ni = 0; ni < 4; ++ni)
        bfr[ni] = *reinterpret_cast<const bf16x8*>(
            &Bs[((wc << 6) + (ni << 4) + (l & 15)) * 64 + k0]);
#pragma unroll
      for (int mi = 0; mi < 4; ++mi)
#pragma unroll
        for (int ni = 0; ni < 4; ++ni)
          acc[mi][ni] = mfma16(af[mi], bfr[ni], acc[mi][ni]);
    }
    __syncthreads();
  }

  if (z < 2) {
    float* dst = (z == 0) ? qproj : kproj;
#pragma unroll
    for (int mi = 0; mi < 4; ++mi)
#pragma unroll
      for (int ni = 0; ni < 4; ++ni)
#pragma unroll
        for (int r = 0; r < 4; ++r) {
          int rowg = brow + (wr << 6) + (mi << 4) + ((l >> 4) << 2) + r;
          int colg = bcol + (wc << 6) + (ni << 4) + (l & 15);
          dst[(size_t)rowg * 1024 + colg] = acc[mi][ni][r];
        }
  } else {
    const int bb = brow >> 11;
    const int nblk = brow & 2047;
#pragma unroll
    for (int mi = 0; mi < 4; ++mi)
#pragma unroll
      for (int ni = 0; ni < 4; ++ni) {
        int n0 = nblk + (wr << 6) + (mi << 4) + ((l >> 4) << 2);
        int colg = bcol + (wc << 6) + (ni << 4) + (l & 15);
        int h = colg >> 6, d = colg & 63;
        ushort4 u;
        u.x = f2bf(acc[mi][ni][0]); u.y = f2bf(acc[mi][ni][1]);
        u.z = f2bf(acc[mi][ni][2]); u.w = f2bf(acc[mi][ni][3]);
        *reinterpret_cast<ushort4*>(
            &vtb[((size_t)(bb * 16 + h) * 64 + d) * 2048 + n0]) = u;
      }
  }
}

// ---------------------------------------------------------------------------
// Per-head LayerNorm (D=64) + optional mup scale, fp32 [R][1024] ->
// bf16 [B,H,L,64].
// ---------------------------------------------------------------------------
template <int DO_SCALE>
__global__ __launch_bounds__(256, 4)
void ln_head(const float* __restrict__ in, unsigned short* __restrict__ out,
             const float* __restrict__ gw, const float* __restrict__ bw)
{
  const int tid = threadIdx.x;
  const int w = tid >> 6, l = tid & 63;
  const int row = blockIdx.x * 4 + w;
  const int h = l >> 2, dq = l & 3;
  const float* src = in + (size_t)row * 1024 + h * 64 + dq * 16;
  const float4* p = reinterpret_cast<const float4*>(src);
  float4 a = p[0], b = p[1], c = p[2], d = p[3];
  float x[16] = {a.x, a.y, a.z, a.w, b.x, b.y, b.z, b.w,
                 c.x, c.y, c.z, c.w, d.x, d.y, d.z, d.w};
  float s = 0.f, s2 = 0.f;
#pragma unroll
  for (int j = 0; j < 16; ++j) { s += x[j]; s2 += x[j] * x[j]; }
  s  += __shfl_xor(s, 1);  s  += __shfl_xor(s, 2);
  s2 += __shfl_xor(s2, 1); s2 += __shfl_xor(s2, 2);
  float mean = s * (1.f / 64.f);
  float var  = s2 * (1.f / 64.f) - mean * mean;
  float rstd = rsqrtf(var + 1e-5f);
  float y[16];
#pragma unroll
  for (int j = 0; j < 16; ++j) {
    float t = (x[j] - mean) * rstd * gw[dq * 16 + j] + bw[dq * 16 + j];
    if (DO_SCALE) t *= 0.125f;
    y[j] = t;
  }
  int bb = row >> 11, n = row & 2047;
  unsigned short* dst = out + (((size_t)(bb * 16 + h) << 11) + n) * 64 + dq * 16;
  int4 o0, o1;
  o0.x = pk2(y[0], y[1]);  o0.y = pk2(y[2], y[3]);
  o0.z = pk2(y[4], y[5]);  o0.w = pk2(y[6], y[7]);
  o1.x = pk2(y[8], y[9]);  o1.y = pk2(y[10], y[11]);
  o1.z = pk2(y[12], y[13]); o1.w = pk2(y[14], y[15]);
  *reinterpret_cast<int4*>(dst) = o0;
  *reinterpret_cast<int4*>(dst + 8) = o1;
}

// ---------------------------------------------------------------------------
// Flash attention, swapped-QK^T 32x32 structure (unchanged except O layout:
// writes [B,N,H*D] flat so gemm_out stages linearly).
// ---------------------------------------------------------------------------
__global__ __launch_bounds__(256, 2)
void attn_fwd(const unsigned short* __restrict__ Q,
              const unsigned short* __restrict__ K,
              const unsigned short* __restrict__ Vt,
              unsigned short* __restrict__ O)
{
  __shared__ short Ks[64 * 64];
  __shared__ short Vs[64 * 64];
  const int tid = threadIdx.x, w = tid >> 6, l = tid & 63;
  const int lo5 = l & 31, hi = l >> 5;
  const int bh = blockIdx.y;
  const int qbase = blockIdx.x * 128 + w * 32;
  const unsigned short* Qg = Q + ((size_t)bh * 2048 + qbase) * 64;
  const unsigned short* Kg = K + (size_t)bh * 2048 * 64;
  const unsigned short* Vg = Vt + (size_t)bh * 64 * 2048;

  bf16x8 qf[4];
#pragma unroll
  for (int ks = 0; ks < 4; ++ks)
    qf[ks] = *reinterpret_cast<const bf16x8*>(Qg + lo5 * 64 + ks * 16 + hi * 8);

  f32x16 oc0 = zero16(), oc1 = zero16();
  float m = -1e30f, lsum = 0.f;

  for (int it = 0; it < 32; ++it) {
#pragma unroll
    for (int i = 0; i < 2; ++i) {
      int cc = i * 256 + tid, row = cc >> 3, c8 = cc & 7;
      int4 dk = *reinterpret_cast<const int4*>(Kg + (it * 64 + row) * 64 + c8 * 8);
      *reinterpret_cast<int4*>(&Ks[(row << 6) + ((c8 << 3) ^ ((row & 7) << 3))]) = dk;
      int4 dv = *reinterpret_cast<const int4*>(Vg + (size_t)row * 2048 + it * 64 + c8 * 8);
      *reinterpret_cast<int4*>(&Vs[(row << 6) + ((c8 << 3) ^ ((row & 7) << 3))]) = dv;
    }
    __syncthreads();

    f32x16 s0 = zero16(), s1 = zero16();
#pragma unroll
    for (int ks = 0; ks < 4; ++ks) {
      const int colc = (16 * ks + 8 * hi) ^ ((lo5 & 7) << 3);
      bf16x8 k0 = *reinterpret_cast<const bf16x8*>(&Ks[(lo5 << 6) + colc]);
      s0 = mfma32(k0, qf[ks], s0);
      bf16x8 k1 = *reinterpret_cast<const bf16x8*>(&Ks[((32 + lo5) << 6) + colc]);
      s1 = mfma32(k1, qf[ks], s1);
    }

    float pm = s0[0];
#pragma unroll
    for (int r = 1; r < 16; ++r) pm = fmaxf(pm, s0[r]);
#pragma unroll
    for (int r = 0; r < 16; ++r) pm = fmaxf(pm, s1[r]);
    pm = fmaxf(pm, __shfl_xor(pm, 32));
    if (!__all(pm <= m + 8.f)) {
      float mn = fmaxf(m, pm);
      float al = __expf(m - mn);
      m = mn; lsum *= al;
#pragma unroll
      for (int r = 0; r < 16; ++r) {
        float ar = __shfl(al, (r & 3) + 8 * (r >> 2) + 4 * hi);
        oc0[r] *= ar; oc1[r] *= ar;
      }
    }

    auto pvsub = [&](const f32x16& sv, int jbase) {
      float p0[16];
#pragma unroll
      for (int r = 0; r < 16; ++r) { p0[r] = __expf(sv[r] - m); lsum += p0[r]; }
#pragma unroll
      for (int f = 0; f < 2; ++f) {
        unsigned x  = pk2(p0[8 * f + 0], p0[8 * f + 1]);
        unsigned zz = pk2(p0[8 * f + 2], p0[8 * f + 3]);
        unsigned y  = pk2(p0[8 * f + 4], p0[8 * f + 5]);
        unsigned ww = pk2(p0[8 * f + 6], p0[8 * f + 7]);
        unsigned xs = (unsigned)__shfl_xor((int)x, 32);
        unsigned zs = (unsigned)__shfl_xor((int)zz, 32);
        unsigned ys = (unsigned)__shfl_xor((int)y, 32);
        unsigned ws = (unsigned)__shfl_xor((int)ww, 32);
        unsigned a0 = hi ? ys : x;
        unsigned a1 = hi ? ws : zz;
        unsigned a2 = hi ? y  : xs;
        unsigned a3 = hi ? ww : zs;
        bf16x8 pa = mk8(a0, a1, a2, a3);
        const int colc = (jbase + 16 * f + 8 * hi);
        bf16x8 v0 = *reinterpret_cast<const bf16x8*>(
            &Vs[(lo5 << 6) + (colc ^ ((lo5 & 7) << 3))]);
        oc0 = mfma32(pa, v0, oc0);
        bf16x8 v1 = *reinterpret_cast<const bf16x8*>(
            &Vs[((32 + lo5) << 6) + (colc ^ ((lo5 & 7) << 3))]);
        oc1 = mfma32(pa, v1, oc1);
      }
    };
    pvsub(s0, 0);
    pvsub(s1, 32);
    __syncthreads();
  }

  lsum += __shfl_xor(lsum, 32);
  float inv = 1.f / lsum;
  // O in [B, N, H*64] flat
  unsigned short* Og = O + ((size_t)(bh >> 4) * 2048 + qbase) * 1024 + (bh & 15) * 64;
#pragma unroll
  for (int r = 0; r < 16; ++r) {
    int qrow = (r & 3) + 8 * (r >> 2) + 4 * hi;
    float ir = __shfl(inv, qrow);
    Og[qrow * 1024 + lo5]      = f2bf(oc0[r] * ir);
    Og[qrow * 1024 + 32 + lo5] = f2bf(oc1[r] * ir);
  }
}

// ---------------------------------------------------------------------------
// Output projection (m97 structure): out = Ocat @ Wp^T + bp, fp32 out.
// A = obuf bf16 [4096][1024], B = wpb bf16 [1024][1024].
// ---------------------------------------------------------------------------
__global__ __launch_bounds__(256, 2)
void gemm_out_bf(const unsigned short* __restrict__ ob,
                 const unsigned short* __restrict__ wpb,
                 const float* __restrict__ bp, float* __restrict__ out)
{
  __shared__ short As[128 * 64];
  __shared__ short Bs[128 * 64];
  const int tid = threadIdx.x;
  const int l = tid & 63, w = tid >> 6;
  const int wr = w >> 1, wc = w & 1;
  const int brow = blockIdx.y * 128, bcol = blockIdx.x * 128;

  const f32x4 zero = {0.f, 0.f, 0.f, 0.f};
  f32x4 acc[4][4];
#pragma unroll
  for (int mi = 0; mi < 4; ++mi)
#pragma unroll
    for (int ni = 0; ni < 4; ++ni) acc[mi][ni] = zero;

  const int srow = w * 32 + (l >> 3);
  const int scol = (l & 7) * 8;

  for (int kt = 0; kt < 16; ++kt) {
    const unsigned short* ga = ob + (size_t)(brow + srow) * 1024 + kt * 64 + scol;
    const unsigned short* gb = wpb + (size_t)(bcol + srow) * 1024 + kt * 64 + scol;
#pragma unroll
    for (int i = 0; i < 4; ++i) {
      gl16(ga + (size_t)i * 8 * 1024, &As[(w * 32 + i * 8) * 64]);
      gl16(gb + (size_t)i * 8 * 1024, &Bs[(w * 32 + i * 8) * 64]);
    }
    __syncthreads();
#pragma unroll
    for (int kk = 0; kk < 2; ++kk) {
      const int k0 = kk * 32 + ((l >> 4) << 3);
      bf16x8 af[4], bfr[4];
#pragma unroll
      for (int mi = 0; mi < 4; ++mi)
        af[mi] = *reinterpret_cast<const bf16x8*>(
            &As[((wr << 6) + (mi << 4) + (l & 15)) * 64 + k0]);
#pragma unroll
      for (int ni = 0; ni < 4; ++ni)
        bfr[ni] = *reinterpret_cast<const bf16x8*>(
            &Bs[((wc << 6) + (ni << 4) + (l & 15)) * 64 + k0]);
#pragma unroll
      for (int mi = 0; mi < 4; ++mi)
#pragma unroll
        for (int ni = 0; ni < 4; ++ni)
          acc[mi][ni] = mfma16(af[mi], bfr[ni], acc[mi][ni]);
    }
    __syncthreads();
  }

  float bias[4];
#pragma unroll
  for (int ni = 0; ni < 4; ++ni)
    bias[ni] = bp[bcol + (wc << 6) + (ni << 4) + (l & 15)];
#pragma unroll
  for (int mi = 0; mi < 4; ++mi)
#pragma unroll
    for (int ni = 0; ni < 4; ++ni)
#pragma unroll
      for (int r = 0; r < 4; ++r) {
        int rowg = brow + (wr << 6) + (mi << 4) + ((l >> 4) << 2) + r;
        int colg = bcol + (wc << 6) + (ni << 4) + (l & 15);
        out[(size_t)rowg * 1024 + colg] = acc[mi][ni][r] + bias[ni];
      }
}

// ---------------------------------------------------------------------------
extern "C" void kernel_launch(void* const* d_in, const int* in_sizes, int n_in,
                              void* d_out, int out_size, void* d_ws, size_t ws_size,
                              hipStream_t stream)
{
  const float* x1 = (const float*)d_in[0];
  const float* x2 = (const float*)d_in[1];
  const float* Wq = (const float*)d_in[2];
  const float* Wk = (const float*)d_in[3];
  const float* Wv = (const float*)d_in[4];
  const float* Wp = (const float*)d_in[5];
  const float* bp = (const float*)d_in[6];
  const float* lg = (const float*)d_in[7];
  const float* lb = (const float*)d_in[8];

  char* wsb = (char*)d_ws;
  unsigned short* xb   = (unsigned short*)wsb;             // 24 MiB (12M ushort)
  float* qproj = (float*)(wsb + 25165824);                 // 16 MiB
  float* kproj = (float*)(wsb + 41943040);                 // 16 MiB
  unsigned short* qb   = (unsigned short*)(wsb + 58720256);// 8 MiB
  unsigned short* kb   = qb + 4194304;                     // 8 MiB
  unsigned short* vtb  = kb + 4194304;                     // 8 MiB (V^T)
  unsigned short* obuf = vtb + 4194304;                    // 8 MiB
  float* out = (float*)d_out;

  conv_bf16<<<6144, 256, 0, stream>>>(x1, x2, Wq, Wk, Wv, Wp, xb);
  gemm_qkv_bf<<<dim3(8, 32, 3), 256, 0, stream>>>(xb, qproj, kproj, vtb);
  ln_head<1><<<1024, 256, 0, stream>>>(qproj, qb, lg, lb);
  ln_head<0><<<1024, 256, 0, stream>>>(kproj, kb, lg, lb);
  attn_fwd<<<dim3(16, 32), 256, 0, stream>>>(qb, kb, vtb, obuf);
  gemm_out_bf<<<dim3(8, 32), 256, 0, stream>>>(obuf,
      xb + 11534336, bp, out);
}